// Round 7
// baseline (190.726 us; speedup 1.0000x reference)
//
#include <hip/hip_runtime.h>
#include <math.h>

// StatefulRosenberg R14: barrier-free k_emit + chain-ordered loads + VPT=16.
//
// Ledger: ~127 us fixed harness overhead; controllable = sums ~13 + emit
// ~40 us vs ~33 us traffic floor. R13 (barrier-free) confirmed: BW 3.04->
// 3.33 TB/s, VALUBusy 23->34, but neutral net -- exposed two next issues:
//  (1) vmcnt ORDER: R13 issued f0,oq,partials but consumed partials FIRST
//      -> first wait = vmcnt(0) -> chain head eats oq's HBM latency.
//      Fix: issue partials (L2) -> f0 (LLC) -> oq (HBM, consumed last);
//      ordered vmcnt then lets the butterfly start after L2 loads only.
//  (2) scan work scales with wave count: f64 shfl scan+butterfly ~36
//      ds_bpermute/wave. VPT 8->16 halves wave count (and predicated
//      partial loads 8->4); intra-wave scan in f32 (lane sums <=3.3e-4,
//      wave total <=2.1e-2, abs err ~1e-9) halves shuffle count again.
//      R10 measured this register shape at 36 VGPR -> fits (256,8)'s 64.
// Kept: f64 base path (butterfly f64: values ~10.9), one f64 wrap + f32
// per-element accumulation (max unwrapped < 1+16/48000 -> one fract),
// regular wav stores (R9: nt-store +30 MB), nt loads on read-once oq,
// f0 regular (LLC warm for pass 2). Dead lanes: grid.sync ~0.13 us/block
// (R8/R12), acquire-spin polling (R8).

constexpr int BATCH   = 16;
constexpr int T       = 1048576;
constexpr int THREADS = 256;
constexpr int VPT     = 16;                // elements per thread
constexpr int CHUNK   = THREADS * VPT;     // 4096
constexpr int NCHUNK  = T / CHUNK;         // 256 chunks per row
constexpr int NGRP    = NCHUNK * 4;        // 1024-elem wave groups per row

#define INV_SR (1.0f / 48000.0f)

typedef float v4f __attribute__((ext_vector_type(4)));

__device__ __forceinline__ double tree8d(const float* s) {
    return (((double)s[0] + (double)s[1]) + ((double)s[2] + (double)s[3]))
         + (((double)s[4] + (double)s[5]) + ((double)s[6] + (double)s[7]));
}

// ---------------- Pass 1: group (1024) + chunk (4096) fp64 sums ----------
__global__ __launch_bounds__(THREADS, 8) void k_sums(
    const float* __restrict__ f0, double* __restrict__ p1024,
    double* __restrict__ p4096)
{
    const int c    = blockIdx.x;
    const int row  = blockIdx.y;
    const int lane = threadIdx.x & 63, wid = threadIdx.x >> 6;
    const v4f* base = (const v4f*)(f0 + (size_t)row * T
                     + (size_t)c * CHUNK + (size_t)threadIdx.x * VPT);
    v4f a0 = base[0], a1 = base[1], a2 = base[2], a3 = base[3];  // warm LLC
    float st[VPT];
    st[ 0]=a0.x*INV_SR; st[ 1]=a0.y*INV_SR; st[ 2]=a0.z*INV_SR; st[ 3]=a0.w*INV_SR;
    st[ 4]=a1.x*INV_SR; st[ 5]=a1.y*INV_SR; st[ 6]=a1.z*INV_SR; st[ 7]=a1.w*INV_SR;
    st[ 8]=a2.x*INV_SR; st[ 9]=a2.y*INV_SR; st[10]=a2.z*INV_SR; st[11]=a2.w*INV_SR;
    st[12]=a3.x*INV_SR; st[13]=a3.y*INV_SR; st[14]=a3.z*INV_SR; st[15]=a3.w*INV_SR;
    double s = tree8d(st) + tree8d(st + 8);
#pragma unroll
    for (int off = 32; off > 0; off >>= 1)
        s += __shfl_xor(s, off, 64);          // all lanes hold wave(1024) sum
    if (lane == 0) p1024[((size_t)row * NCHUNK + c) * 4 + wid] = s;
    __shared__ double ws[THREADS / 64];
    if (lane == 0) ws[wid] = s;
    __syncthreads();
    if (threadIdx.x == 0)
        p4096[(size_t)row * NCHUNK + c] = (ws[0] + ws[1]) + (ws[2] + ws[3]);
}

// ---------------- Pass 2: wave-independent prefix + emit -----------------
__global__ __launch_bounds__(THREADS, 8) void k_emit(
    const float* __restrict__ f0, const float* __restrict__ oq,
    const double* __restrict__ p1024, const double* __restrict__ p4096,
    const float* __restrict__ phase_state,
    float* __restrict__ wav, float* __restrict__ next_state)
{
    const int c    = blockIdx.x;
    const int row  = blockIdx.y;
    const int lane = threadIdx.x & 63, wid = threadIdx.x >> 6;
    const size_t base_idx = (size_t)row * T + (size_t)c * CHUNK
                          + (size_t)wid * 1024 + (size_t)lane * VPT;

    // ---- loads in CHAIN-CRITICAL order (vmcnt is ordered: oldest first) --
    // (1) chunk-prefix partials: L2-hot, head of the dependency chain
    const double* pp = p4096 + (size_t)row * NCHUNK;
    double pv = 0.0;
#pragma unroll
    for (int k = 0; k < 4; ++k) {
        int j = lane + 64 * k;
        if (j < c) pv += pp[j];
    }
    // (2) sibling wave groups within this chunk (wave-uniform)
    const double* sp = p1024 + ((size_t)row * NCHUNK + c) * 4;
    double sib = 0.0;
    if (wid > 0) sib += sp[0];
    if (wid > 1) sib += sp[1];
    if (wid > 2) sib += sp[2];
    const float pstate = phase_state[row];
    // (3) f0: LLC-hot, needed for lane sums / scan
    const v4f* fb = (const v4f*)(f0 + base_idx);
    v4f f_0 = fb[0], f_1 = fb[1], f_2 = fb[2], f_3 = fb[3];
    // (4) oq: HBM, consumed LAST (pulse loop) -> its latency hides under
    //     the butterfly + scan instead of blocking them
    const v4f* ob = (const v4f*)(oq + base_idx);
    v4f o_0 = __builtin_nontemporal_load(ob + 0);
    v4f o_1 = __builtin_nontemporal_load(ob + 1);
    v4f o_2 = __builtin_nontemporal_load(ob + 2);
    v4f o_3 = __builtin_nontemporal_load(ob + 3);

    // ---- f64 chunk-prefix butterfly (values up to ~10.9: stays f64) -----
#pragma unroll
    for (int off = 32; off > 0; off >>= 1)
        pv += __shfl_xor(pv, off, 64);

    // ---- f32 steps + f32 intra-wave scan (lane sums <=3.3e-4) -----------
    float st[VPT];
    st[ 0]=f_0.x*INV_SR; st[ 1]=f_0.y*INV_SR; st[ 2]=f_0.z*INV_SR; st[ 3]=f_0.w*INV_SR;
    st[ 4]=f_1.x*INV_SR; st[ 5]=f_1.y*INV_SR; st[ 6]=f_1.z*INV_SR; st[ 7]=f_1.w*INV_SR;
    st[ 8]=f_2.x*INV_SR; st[ 9]=f_2.y*INV_SR; st[10]=f_2.z*INV_SR; st[11]=f_2.w*INV_SR;
    st[12]=f_3.x*INV_SR; st[13]=f_3.y*INV_SR; st[14]=f_3.z*INV_SR; st[15]=f_3.w*INV_SR;
    float ts32 = (((st[0]+st[1])+(st[2]+st[3])) + ((st[4]+st[5])+(st[6]+st[7])))
               + (((st[8]+st[9])+(st[10]+st[11])) + ((st[12]+st[13])+(st[14]+st[15])));
    float inc = ts32;
#pragma unroll
    for (int off = 1; off < 64; off <<= 1) {
        float n = __shfl_up(inc, off, 64);
        if (lane >= off) inc += n;
    }

    const double base = (double)pstate + pv + sib;
    const double run  = base + (double)(inc - ts32);

    // next_state: unwrapped final row phase (c=last, wid=3, lane=63)
    if (c == NCHUNK - 1 && wid == 3 && lane == 63)
        next_state[row] = (float)(base + (double)inc);

    // wrap thread base ONCE in f64; f32 per-element accumulation
    // (max unwrapped < 1 + 16/48000 -> single fract suffices)
    float runf = (float)(run - floor(run));

    float o[VPT];
    o[ 0]=o_0.x; o[ 1]=o_0.y; o[ 2]=o_0.z; o[ 3]=o_0.w;
    o[ 4]=o_1.x; o[ 5]=o_1.y; o[ 6]=o_1.z; o[ 7]=o_1.w;
    o[ 8]=o_2.x; o[ 9]=o_2.y; o[10]=o_2.z; o[11]=o_2.w;
    o[12]=o_3.x; o[13]=o_3.y; o[14]=o_3.z; o[15]=o_3.w;

    float outv[VPT];
#pragma unroll
    for (int i = 0; i < VPT; ++i) {
        runf += st[i];
        float ph  = __builtin_amdgcn_fractf(runf);     // wrapped phase [0,1)
        float oqv = o[i];
        float tp  = oqv * 0.66f;
        bool  is_rise  = ph < tp;
        bool  in_pulse = ph < oqv;
        float num = is_rise ? ph : (ph - tp);
        float den = is_rise ? fmaf(oqv, 0.66f, 1e-6f)    // tp + eps
                            : fmaf(oqv, 0.68f, 1e-6f);   // 2*tn + eps
        float rev = 0.5f * num * __builtin_amdgcn_rcpf(den);
        float c2  = __builtin_amdgcn_cosf(rev);
        outv[i] = is_rise ? 0.5f * (1.0f - c2) : (in_pulse ? c2 : 0.0f);
    }

    v4f* wb = (v4f*)(wav + base_idx);
#pragma unroll
    for (int j = 0; j < VPT / 4; ++j) {
        v4f vv;
        vv.x = outv[4 * j + 0]; vv.y = outv[4 * j + 1];
        vv.z = outv[4 * j + 2]; vv.w = outv[4 * j + 3];
        wb[j] = vv;   // regular stores: L2 merges partial lines (R9)
    }
}

// ================= Fallback: R11 two-kernel path (proven, 174.8 us) ======
constexpr int VPT_FB    = 8;
constexpr int CHUNK_FB  = THREADS * VPT_FB;   // 2048
constexpr int NCHUNK_FB = T / CHUNK_FB;       // 512

__global__ __launch_bounds__(THREADS, 8) void k_chunk_sums_fb(
    const float* __restrict__ f0, double* __restrict__ partial)
{
    const int chunk = blockIdx.x;
    const int row   = blockIdx.y;
    const v4f* base = (const v4f*)(f0 + (size_t)row * T
                     + (size_t)chunk * CHUNK_FB + (size_t)threadIdx.x * VPT_FB);
    v4f v0 = base[0], v1 = base[1];
    float st[VPT_FB];
    st[0]=v0.x*INV_SR; st[1]=v0.y*INV_SR; st[2]=v0.z*INV_SR; st[3]=v0.w*INV_SR;
    st[4]=v1.x*INV_SR; st[5]=v1.y*INV_SR; st[6]=v1.z*INV_SR; st[7]=v1.w*INV_SR;
    double s = tree8d(st);
#pragma unroll
    for (int off = 32; off > 0; off >>= 1)
        s += __shfl_down(s, off, 64);
    __shared__ double ws[THREADS / 64];
    const int lane = threadIdx.x & 63, wid = threadIdx.x >> 6;
    if (lane == 0) ws[wid] = s;
    __syncthreads();
    if (threadIdx.x == 0)
        partial[row * NCHUNK_FB + chunk] = ws[0] + ws[1] + ws[2] + ws[3];
}

__global__ __launch_bounds__(THREADS, 8) void k_emit_fb(
    const float* __restrict__ f0, const float* __restrict__ oq,
    const double* __restrict__ partial, const float* __restrict__ phase_state,
    float* __restrict__ wav, float* __restrict__ next_state)
{
    const int chunk = blockIdx.x;
    const int row   = blockIdx.y;
    const int lane  = threadIdx.x & 63, wid = threadIdx.x >> 6;
    const size_t base_idx = (size_t)row * T + (size_t)chunk * CHUNK_FB
                          + (size_t)threadIdx.x * VPT_FB;
    __shared__ double rs[THREADS / 64];
    __shared__ double ws[THREADS / 64];

    const v4f* fb = (const v4f*)(f0 + base_idx);
    v4f f_0 = fb[0], f_1 = fb[1];
    const v4f* ob = (const v4f*)(oq + base_idx);
    v4f o_0 = __builtin_nontemporal_load(ob + 0);
    v4f o_1 = __builtin_nontemporal_load(ob + 1);
    double pv = 0.0;
    if ((int)threadIdx.x < chunk)       pv  = partial[row * NCHUNK_FB + threadIdx.x];
    if ((int)threadIdx.x + 256 < chunk) pv += partial[row * NCHUNK_FB + threadIdx.x + 256];
    const float pstate = phase_state[row];

    float st[VPT_FB];
    st[0]=f_0.x*INV_SR; st[1]=f_0.y*INV_SR; st[2]=f_0.z*INV_SR; st[3]=f_0.w*INV_SR;
    st[4]=f_1.x*INV_SR; st[5]=f_1.y*INV_SR; st[6]=f_1.z*INV_SR; st[7]=f_1.w*INV_SR;
    double tsum = tree8d(st);
#pragma unroll
    for (int off = 32; off > 0; off >>= 1)
        pv += __shfl_down(pv, off, 64);
    if (lane == 0) rs[wid] = pv;
    double inc = tsum;
#pragma unroll
    for (int off = 1; off < 64; off <<= 1) {
        double n = __shfl_up(inc, off, 64);
        if (lane >= off) inc += n;
    }
    if (lane == 63) ws[wid] = inc;
    __syncthreads();
    const double chunkpref = rs[0] + rs[1] + rs[2] + rs[3];
    double run = (double)pstate + chunkpref + (inc - tsum);
#pragma unroll
    for (int w = 0; w < THREADS / 64; ++w)
        if (w < wid) run += ws[w];
    if (chunk == NCHUNK_FB - 1 && threadIdx.x == 0)
        next_state[row] = (float)((double)pstate + chunkpref
                                  + ws[0] + ws[1] + ws[2] + ws[3]);
    float runf = (float)(run - floor(run));
    float o[VPT_FB];
    o[0]=o_0.x; o[1]=o_0.y; o[2]=o_0.z; o[3]=o_0.w;
    o[4]=o_1.x; o[5]=o_1.y; o[6]=o_1.z; o[7]=o_1.w;
    float outv[VPT_FB];
#pragma unroll
    for (int i = 0; i < VPT_FB; ++i) {
        runf += st[i];
        float ph  = __builtin_amdgcn_fractf(runf);
        float oqv = o[i];
        float tp  = oqv * 0.66f;
        bool  is_rise  = ph < tp;
        bool  in_pulse = ph < oqv;
        float num = is_rise ? ph : (ph - tp);
        float den = is_rise ? fmaf(oqv, 0.66f, 1e-6f)
                            : fmaf(oqv, 0.68f, 1e-6f);
        float rev = 0.5f * num * __builtin_amdgcn_rcpf(den);
        float c2  = __builtin_amdgcn_cosf(rev);
        outv[i] = is_rise ? 0.5f * (1.0f - c2) : (in_pulse ? c2 : 0.0f);
    }
    v4f* wb = (v4f*)(wav + base_idx);
    v4f w0; w0.x=outv[0]; w0.y=outv[1]; w0.z=outv[2]; w0.w=outv[3];
    v4f w1; w1.x=outv[4]; w1.y=outv[5]; w1.z=outv[6]; w1.w=outv[7];
    wb[0] = w0; wb[1] = w1;
}

extern "C" void kernel_launch(void* const* d_in, const int* in_sizes, int n_in,
                              void* d_out, int out_size, void* d_ws, size_t ws_size,
                              hipStream_t stream)
{
    const float* f0          = (const float*)d_in[0];
    const float* oq          = (const float*)d_in[1];
    const float* phase_state = (const float*)d_in[2];
    float* wav = (float*)d_out;
    float* ns  = wav + (size_t)BATCH * T;

    const size_t need = (size_t)BATCH * NCHUNK * 4 * sizeof(double)   // p1024 128 KB
                      + (size_t)BATCH * NCHUNK * sizeof(double);      // p4096  32 KB
    if (ws_size >= need) {
        double* p1024 = (double*)d_ws;
        double* p4096 = p1024 + (size_t)BATCH * NCHUNK * 4;
        dim3 grid(NCHUNK, BATCH);
        k_sums<<<grid, THREADS, 0, stream>>>(f0, p1024, p4096);
        k_emit<<<grid, THREADS, 0, stream>>>(f0, oq, p1024, p4096, phase_state,
                                             wav, ns);
    } else {
        double* partial = (double*)d_ws;   // 64 KB
        dim3 grid(NCHUNK_FB, BATCH);
        k_chunk_sums_fb<<<grid, THREADS, 0, stream>>>(f0, partial);
        k_emit_fb<<<grid, THREADS, 0, stream>>>(f0, oq, partial, phase_state,
                                                wav, ns);
    }
}

// Round 8
// 174.088 us; speedup vs baseline: 1.0956x; 1.0956x over previous
//
#include <hip/hip_runtime.h>
#include <math.h>

// StatefulRosenberg R15: restore R11 (best measured: 174.8 us total,
// emit ~35-36 us) + chain-critical load order in k_emit.
//
// Ledger of dead lanes (all measured):
//   - grid.sync / spin-wait: ~0.13 us per participating block (R8: 470us,
//     R12: 147us). Never again at O(1000) blocks.
//   - barrier-free per-wave prefix (R13/R14): replicates chunk-prefix
//     butterfly per WAVE (4x predicated loads, 4x f64 shfl = 2x bpermute
//     each, on LDS hw anyway). Block LDS scan + 1 barrier is cheaper.
//   - VPT=16 (R14): f0 re-read loses LLC residency (FETCH +25 MB).
//   - nt wav stores (R9): partial-line streaming, WRITE +30 MB.
//   - oq hoist pre-scan (R9): KEEP (+0.25 TB/s, latency under scan).
// R15's one change vs R11: issue order f0 -> partials -> oq (was
// f0 -> oq -> partials). vmcnt is ordered; the butterfly consumed the
// NEWEST loads and so waited vmcnt(0), eating oq's HBM latency. Now the
// butterfly waits only on L2-hot partial loads; oq latency hides under
// butterfly + scan + barrier, consumed last by the pulse loop.

constexpr int BATCH   = 16;
constexpr int T       = 1048576;
constexpr int THREADS = 256;
constexpr int VPT     = 8;                // elements per thread
constexpr int CHUNK   = THREADS * VPT;    // 2048
constexpr int NCHUNK  = T / CHUNK;        // 512

#define INV_SR (1.0f / 48000.0f)

typedef float v4f __attribute__((ext_vector_type(4)));

__device__ __forceinline__ double tree8d(const float* s) {
    return (((double)s[0] + (double)s[1]) + ((double)s[2] + (double)s[3]))
         + (((double)s[4] + (double)s[5]) + ((double)s[6] + (double)s[7]));
}

// ---------------- Pass 1: per-chunk fp64 sums ----------------
__global__ __launch_bounds__(THREADS, 8) void k_chunk_sums(
    const float* __restrict__ f0, double* __restrict__ partial)
{
    const int chunk = blockIdx.x;
    const int row   = blockIdx.y;
    const v4f* base = (const v4f*)(f0 + (size_t)row * T
                     + (size_t)chunk * CHUNK + (size_t)threadIdx.x * VPT);
    v4f v0 = base[0], v1 = base[1];       // regular loads: warm LLC for pass 2
    float st[VPT];
    st[0]=v0.x*INV_SR; st[1]=v0.y*INV_SR; st[2]=v0.z*INV_SR; st[3]=v0.w*INV_SR;
    st[4]=v1.x*INV_SR; st[5]=v1.y*INV_SR; st[6]=v1.z*INV_SR; st[7]=v1.w*INV_SR;
    double s = tree8d(st);
#pragma unroll
    for (int off = 32; off > 0; off >>= 1)
        s += __shfl_down(s, off, 64);
    __shared__ double ws[THREADS / 64];
    const int lane = threadIdx.x & 63, wid = threadIdx.x >> 6;
    if (lane == 0) ws[wid] = s;
    __syncthreads();
    if (threadIdx.x == 0)
        partial[row * NCHUNK + chunk] = ws[0] + ws[1] + ws[2] + ws[3];
}

// ---------------- Pass 2: prefix + intra-chunk scan + Rosenberg pulse ----
__global__ __launch_bounds__(THREADS, 8) void k_emit(
    const float* __restrict__ f0, const float* __restrict__ oq,
    const double* __restrict__ partial, const float* __restrict__ phase_state,
    float* __restrict__ wav, float* __restrict__ next_state)
{
    const int chunk = blockIdx.x;
    const int row   = blockIdx.y;
    const int lane  = threadIdx.x & 63, wid = threadIdx.x >> 6;
    const size_t base_idx = (size_t)row * T + (size_t)chunk * CHUNK
                          + (size_t)threadIdx.x * VPT;

    __shared__ double rs[THREADS / 64];   // chunk-prefix partial reduce
    __shared__ double ws[THREADS / 64];   // wave inclusive totals

    // ---- loads in CHAIN-CRITICAL order (vmcnt is ordered, oldest first):
    // (1) f0 -- first consumer (st / tsum); LLC-hot from pass 1
    const v4f* fb = (const v4f*)(f0 + base_idx);
    v4f f_0 = fb[0], f_1 = fb[1];
    // (2) chunk-prefix partials -- second consumer (butterfly); L2-hot
    double pv = 0.0;
    if ((int)threadIdx.x < chunk)       pv  = partial[row * NCHUNK + threadIdx.x];
    if ((int)threadIdx.x + 256 < chunk) pv += partial[row * NCHUNK + threadIdx.x + 256];
    const float pstate = phase_state[row];
    // (3) oq -- consumed LAST (pulse loop); HBM latency hides under
    //     butterfly + scan + barrier instead of blocking them
    const v4f* ob = (const v4f*)(oq + base_idx);
    v4f o_0 = __builtin_nontemporal_load(ob + 0);
    v4f o_1 = __builtin_nontemporal_load(ob + 1);

    // ---- f32 steps (match ref rounding scale) + thread fp64 sum ----
    float st[VPT];
    st[0]=f_0.x*INV_SR; st[1]=f_0.y*INV_SR; st[2]=f_0.z*INV_SR; st[3]=f_0.w*INV_SR;
    st[4]=f_1.x*INV_SR; st[5]=f_1.y*INV_SR; st[6]=f_1.z*INV_SR; st[7]=f_1.w*INV_SR;
    double tsum = tree8d(st);

    // ---- chunk prefix: parallel reduce of partial[row][0..chunk-1] ----
#pragma unroll
    for (int off = 32; off > 0; off >>= 1)
        pv += __shfl_down(pv, off, 64);
    if (lane == 0) rs[wid] = pv;

    // ---- block exclusive scan of per-thread sums ----
    double inc = tsum;
#pragma unroll
    for (int off = 1; off < 64; off <<= 1) {
        double n = __shfl_up(inc, off, 64);
        if (lane >= off) inc += n;
    }
    if (lane == 63) ws[wid] = inc;
    __syncthreads();

    const double chunkpref = rs[0] + rs[1] + rs[2] + rs[3];
    double run = (double)pstate + chunkpref + (inc - tsum);
#pragma unroll
    for (int w = 0; w < THREADS / 64; ++w)
        if (w < wid) run += ws[w];

    // next_state: unwrapped final phase, written by the last chunk's thread 0
    if (chunk == NCHUNK - 1 && threadIdx.x == 0)
        next_state[row] = (float)((double)pstate + chunkpref
                                  + ws[0] + ws[1] + ws[2] + ws[3]);

    // wrap the thread base ONCE in f64; per-element accumulation is f32.
    // max unwrapped value < 1 + 8*(1/48000) -> single fract suffices.
    float runf = (float)(run - floor(run));

    float o[VPT];
    o[0]=o_0.x; o[1]=o_0.y; o[2]=o_0.z; o[3]=o_0.w;
    o[4]=o_1.x; o[5]=o_1.y; o[6]=o_1.z; o[7]=o_1.w;

    // ---- accumulate + pulse; one v_cos per element, arg in revolutions ----
    float outv[VPT];
#pragma unroll
    for (int i = 0; i < VPT; ++i) {
        runf += st[i];
        float ph  = __builtin_amdgcn_fractf(runf);   // wrapped phase in [0,1)
        float oqv = o[i];
        float tp  = oqv * 0.66f;
        bool  is_rise  = ph < tp;
        bool  in_pulse = ph < oqv;
        float num = is_rise ? ph : (ph - tp);
        float den = is_rise ? fmaf(oqv, 0.66f, 1e-6f)    // tp + eps
                            : fmaf(oqv, 0.68f, 1e-6f);   // 2*tn + eps
        // cos(pi * num/den) == v_cos(0.5 * num/den revolutions)
        float rev = 0.5f * num * __builtin_amdgcn_rcpf(den);
        float c2  = __builtin_amdgcn_cosf(rev);
        outv[i] = is_rise ? 0.5f * (1.0f - c2) : (in_pulse ? c2 : 0.0f);
    }

    v4f* wb = (v4f*)(wav + base_idx);
#pragma unroll
    for (int j = 0; j < VPT / 4; ++j) {
        v4f vv;
        vv.x = outv[4 * j + 0]; vv.y = outv[4 * j + 1];
        vv.z = outv[4 * j + 2]; vv.w = outv[4 * j + 3];
        wb[j] = vv;   // regular store: L2 merges partial lines (R9 lesson)
    }
}

extern "C" void kernel_launch(void* const* d_in, const int* in_sizes, int n_in,
                              void* d_out, int out_size, void* d_ws, size_t ws_size,
                              hipStream_t stream)
{
    const float* f0          = (const float*)d_in[0];
    const float* oq          = (const float*)d_in[1];
    const float* phase_state = (const float*)d_in[2];
    float* out = (float*)d_out;                 // [B*T] wav, then [B] next_state

    double* partial = (double*)d_ws;            // B*NCHUNK doubles (64 KB)

    dim3 grid(NCHUNK, BATCH);
    k_chunk_sums<<<grid, THREADS, 0, stream>>>(f0, partial);
    k_emit<<<grid, THREADS, 0, stream>>>(f0, oq, partial, phase_state,
                                         out, out + (size_t)BATCH * T);
}